// Round 5
// baseline (697.718 us; speedup 1.0000x reference)
//
#include <hip/hip_runtime.h>

#define HID 64
#define STRIDE 128   // dst nodes per bucket
#define NPART 8      // XCD partitions
#define MAXNBK 1024
typedef unsigned int u32;

// ---------------------------------------------------------------- degree
__global__ __launch_bounds__(256) void count_deg(const int* __restrict__ dst,
                                                 int* __restrict__ deg, int E) {
  int i = blockIdx.x * 256 + threadIdx.x;
  const int stride = gridDim.x * 256;
  for (; i < E; i += stride) atomicAdd(&deg[dst[i]], 1);
}

__global__ __launch_bounds__(256) void compute_dinv(const int* __restrict__ deg,
                                                    float* __restrict__ dinv, int n) {
  const int i = blockIdx.x * 256 + threadIdx.x;
  if (i < n) dinv[i] = rsqrtf((float)(deg[i] + 1));  // +1 self-loop
}

// ---------------------------------------------------------------- scan (rowptr)
__global__ __launch_bounds__(256) void scan_blocks(const int* __restrict__ deg,
                                                   int* __restrict__ rowptr,
                                                   int* __restrict__ bsum, int n) {
  __shared__ int s[256];
  const int t = threadIdx.x;
  const int i = blockIdx.x * 256 + t;
  const int v = (i < n) ? deg[i] : 0;
  s[t] = v;
  __syncthreads();
  for (int off = 1; off < 256; off <<= 1) {
    const int u = (t >= off) ? s[t - off] : 0;
    __syncthreads();
    s[t] += u;
    __syncthreads();
  }
  if (i < n) rowptr[i] = s[t] - v;
  if (t == 255) bsum[blockIdx.x] = s[255];
}

__global__ __launch_bounds__(512) void scan_top(int* bsum, int nb) {
  __shared__ int s[512];
  const int t = threadIdx.x;
  const int v = (t < nb) ? bsum[t] : 0;
  s[t] = v;
  __syncthreads();
  for (int off = 1; off < 512; off <<= 1) {
    const int u = (t >= off) ? s[t - off] : 0;
    __syncthreads();
    s[t] += u;
    __syncthreads();
  }
  if (t < nb) bsum[t] = s[t] - v;
}

__global__ __launch_bounds__(256) void add_offsets(int* __restrict__ rowptr,
                                                   const int* __restrict__ bsum,
                                                   int n, int E) {
  const int i = blockIdx.x * 256 + threadIdx.x;
  if (i < n) rowptr[i] += bsum[blockIdx.x];
  if (i == 0) rowptr[n] = E;
}

// ---------------------------------------------------------------- per-(bucket,partition) count
// cnt layout [p][b] (partition-major): counter lines are XCD-private
__global__ __launch_bounds__(256) void count_bp(const int* __restrict__ dst,
                                                int* __restrict__ cnt,
                                                int E, int nbk) {
  __shared__ int lc[MAXNBK];
  const int t = threadIdx.x;
  for (int i = t; i < MAXNBK; i += 256) lc[i] = 0;
  __syncthreads();
  const int stride = gridDim.x * 256;
  for (int i = blockIdx.x * 256 + t; i < E; i += stride)
    atomicAdd(&lc[dst[i] >> 7], 1);
  __syncthreads();
  const int p = blockIdx.x & (NPART - 1);
  for (int b = t; b < nbk; b += 256)
    if (lc[b]) atomicAdd(&cnt[p * nbk + b], lc[b]);
}

// ---------------------------------------------------------------- scan counts (bucket-major)
// off[j], j = b*8+p : bucket b's 8 partition segments contiguous.
// also inits cursors cur[p][b] (partition-major).
__global__ __launch_bounds__(256) void scan_bp(const int* __restrict__ cnt,
                                               int* __restrict__ off,
                                               int* __restrict__ cur, int nbk) {
  __shared__ int ps[256];
  const int t = threadIdx.x;
  const int NE = nbk * NPART;
  const int CH = (NE + 255) / 256;
  int s = 0;
  for (int k = 0; k < CH; ++k) {
    const int j = t * CH + k;
    if (j < NE) s += cnt[(j & 7) * nbk + (j >> 3)];
  }
  ps[t] = s;
  __syncthreads();
  for (int o = 1; o < 256; o <<= 1) {
    const int u = (t >= o) ? ps[t - o] : 0;
    __syncthreads();
    ps[t] += u;
    __syncthreads();
  }
  int run = ps[t] - s;  // exclusive prefix of this thread's chunk
  for (int k = 0; k < CH; ++k) {
    const int j = t * CH + k;
    if (j < NE) {
      const int b = j >> 3, p = j & 7;
      const int c = cnt[p * nbk + b];
      off[j] = run;
      cur[p * nbk + b] = run;
      run += c;
    }
  }
  if (t == 255) off[NE] = run;  // == E
}

// ---------------------------------------------------------------- bucket edges, XCD-private fronts
// packed u32: (dstLocal<<17) | src   (src < 2^17, dstLocal < 128)
__global__ __launch_bounds__(256) void bucket_edges_p(const int* __restrict__ src,
                                                      const int* __restrict__ dst,
                                                      int* __restrict__ cur,
                                                      u32* __restrict__ pairs,
                                                      int E, int nbk) {
  const int p = blockIdx.x & (NPART - 1);
  int* mycur = cur + p * nbk;
  int i = blockIdx.x * 256 + threadIdx.x;
  const int stride = gridDim.x * 256;
  for (; i < E; i += stride) {
    const int d = dst[i];
    const int pos = atomicAdd(&mycur[d >> 7], 1);
    pairs[pos] = ((u32)(d & (STRIDE - 1)) << 17) | (u32)src[i];
  }
}

// ---------------------------------------------------------------- exact CSR fill per bucket
// bucket b's region = [off[b*8], off[(b+1)*8]) ; writes stay in a ~16KB window
__global__ __launch_bounds__(256) void local_fill(const u32* __restrict__ pairs,
                                                  const int* __restrict__ off,
                                                  const int* __restrict__ rowptr,
                                                  int* __restrict__ colidx, int n) {
  __shared__ int lcur[STRIDE];
  const int bkt = blockIdx.x;
  const int base = bkt * STRIDE;
  const int t = threadIdx.x;
  if (t < STRIDE) {
    const int node = base + t;
    lcur[t] = (node < n) ? rowptr[node] : 0;
  }
  __syncthreads();
  const int beg = off[bkt * 8], end = off[(bkt + 1) * 8];
  for (int e = beg + t; e < end; e += 256) {
    const u32 p = pairs[e];
    const int pos = atomicAdd(&lcur[p >> 17], 1);
    colidx[pos] = (int)(p & 0x1FFFF);
  }
}

// ---------------------------------------------------------------- dense transform
// out[i, c] = dinv[i] * sum_k x[i,k] * W[k,c]
template <int K>
__global__ __launch_bounds__(256) void gemm_nodes(const float* __restrict__ x,
                                                  const float* __restrict__ W,
                                                  const float* __restrict__ dinv,
                                                  float* __restrict__ out) {
  __shared__ float Wl[K * 64];
  __shared__ float xl[16][K];
  const int tid = threadIdx.x;
  for (int i = tid; i < K * 16; i += 256)
    reinterpret_cast<float4*>(Wl)[i] = reinterpret_cast<const float4*>(W)[i];
  const int row0 = blockIdx.x * 16;
  for (int i = tid; i < 16 * (K / 4); i += 256) {
    const int r = i / (K / 4), q = i % (K / 4);
    reinterpret_cast<float4*>(&xl[r][0])[q] =
        reinterpret_cast<const float4*>(x + (size_t)(row0 + r) * K)[q];
  }
  __syncthreads();
  const int c = tid & 63;
  const int rbase = tid >> 6;
  for (int rr = rbase; rr < 16; rr += 4) {
    float acc = 0.f;
#pragma unroll
    for (int k = 0; k < K; k += 4) {
      const float4 xv = *reinterpret_cast<const float4*>(&xl[rr][k]);
      acc = fmaf(xv.x, Wl[(k + 0) * 64 + c], acc);
      acc = fmaf(xv.y, Wl[(k + 1) * 64 + c], acc);
      acc = fmaf(xv.z, Wl[(k + 2) * 64 + c], acc);
      acc = fmaf(xv.w, Wl[(k + 3) * 64 + c], acc);
    }
    const int grow = row0 + rr;
    out[(size_t)grow * 64 + c] = acc * dinv[grow];
  }
}

// ---------------------------------------------------------------- pull aggregation
// out[d,lane] = relu( dinv[d] * (sum_{s in N(d)} g[s,lane] + g[d,lane]) + b[lane] )
__global__ __launch_bounds__(256) void gather_agg(const int* __restrict__ rowptr,
                                                  const int* __restrict__ colidx,
                                                  const float* __restrict__ g,
                                                  const float* __restrict__ dinv,
                                                  const float* __restrict__ b,
                                                  float* __restrict__ out, int n) {
  const int lane = threadIdx.x & 63;
  const int node = (blockIdx.x * 256 + threadIdx.x) >> 6;
  if (node >= n) return;
  const int beg = rowptr[node];
  const int end = rowptr[node + 1];
  float acc = 0.f;
  int e = beg;
  for (; e + 4 <= end; e += 4) {  // 4-deep ILP to hide gather latency
    const int s0 = colidx[e + 0], s1 = colidx[e + 1];
    const int s2 = colidx[e + 2], s3 = colidx[e + 3];
    const float v0 = g[(size_t)s0 * HID + lane];
    const float v1 = g[(size_t)s1 * HID + lane];
    const float v2 = g[(size_t)s2 * HID + lane];
    const float v3 = g[(size_t)s3 * HID + lane];
    acc += (v0 + v1) + (v2 + v3);
  }
  for (; e < end; ++e) acc += g[(size_t)colidx[e] * HID + lane];
  acc += g[(size_t)node * HID + lane];  // self-loop
  const float r = fmaf(acc, dinv[node], b[lane]);
  out[(size_t)node * HID + lane] = fmaxf(r, 0.f);
}

// ---------------------------------------------------------------- final FC (64 -> 11)
__global__ __launch_bounds__(256) void gemm_fc(const float* __restrict__ h,
                                               const float* __restrict__ W,
                                               const float* __restrict__ b,
                                               float* __restrict__ out) {
  __shared__ float Wl[772];
  __shared__ float xl[16][68];
  const int tid = threadIdx.x;
  for (int i = tid; i < 772; i += 256) Wl[i] = 0.f;
  __syncthreads();
  for (int i = tid; i < 64 * 11; i += 256) Wl[(i / 11) * 12 + (i % 11)] = W[i];
  const int row0 = blockIdx.x * 16;
  for (int i = tid; i < 16 * 16; i += 256) {
    const int r = i >> 4, q = i & 15;
    const float4 v = reinterpret_cast<const float4*>(h + (size_t)(row0 + r) * 64)[q];
    xl[r][q * 4 + 0] = v.x; xl[r][q * 4 + 1] = v.y;
    xl[r][q * 4 + 2] = v.z; xl[r][q * 4 + 3] = v.w;
  }
  __syncthreads();
  const int r = tid >> 4, c = tid & 15;
  float acc = 0.f;
#pragma unroll
  for (int k = 0; k < 64; k += 4) {
    acc = fmaf(xl[r][k + 0], Wl[(k + 0) * 12 + c], acc);
    acc = fmaf(xl[r][k + 1], Wl[(k + 1) * 12 + c], acc);
    acc = fmaf(xl[r][k + 2], Wl[(k + 2) * 12 + c], acc);
    acc = fmaf(xl[r][k + 3], Wl[(k + 3) * 12 + c], acc);
  }
  if (c < 11) out[(size_t)(row0 + r) * 11 + c] = acc + b[c];
}

// ---------------------------------------------------------------- launch
extern "C" void kernel_launch(void* const* d_in, const int* in_sizes, int n_in,
                              void* d_out, int out_size, void* d_ws, size_t ws_size,
                              hipStream_t stream) {
  const float* x   = (const float*)d_in[0];
  const int*   ei  = (const int*)d_in[1];   // [2, E] int32
  const float* W1  = (const float*)d_in[2];
  const float* b1  = (const float*)d_in[3];
  const float* W2  = (const float*)d_in[4];
  const float* b2  = (const float*)d_in[5];
  const float* Wfc = (const float*)d_in[6];
  const float* bfc = (const float*)d_in[7];
  float* out = (float*)d_out;

  const int n = in_sizes[0] / 128;  // 100000
  const int E = in_sizes[1] / 2;    // 3200000
  const int* src = ei;
  const int* dst = ei + E;
  const int nbk = (n + STRIDE - 1) / STRIDE;  // 782 buckets
  const int NE = nbk * NPART;                 // 6256 segments

  char* ws = (char*)d_ws;
  size_t o = 0;
  auto alloc = [&](size_t bytes) {
    char* p = ws + o;
    o += (bytes + 255) & ~(size_t)255;
    return p;
  };
  int*   deg    = (int*)  alloc((size_t)n * 4);
  float* dinv   = (float*)alloc((size_t)n * 4);
  int*   rowptr = (int*)  alloc((size_t)(n + 1) * 4);
  int*   bsum   = (int*)  alloc(512 * 4);
  int*   cnt    = (int*)  alloc((size_t)NE * 4);        // [p][b]
  int*   off    = (int*)  alloc((size_t)(NE + 1) * 4);  // bucket-major
  int*   cur    = (int*)  alloc((size_t)NE * 4);        // [p][b]
  u32*   pairs  = (u32*)  alloc((size_t)E * 4);
  int*   colidx = (int*)  alloc((size_t)E * 4);
  float* B0     = (float*)alloc((size_t)n * HID * 4);
  float* B1     = (float*)alloc((size_t)n * HID * 4);
  if (o > ws_size) return;

  const int nb = (n + 255) / 256;  // 391 scan blocks
  const int gblocks = n / 16;      // 6250 gemm blocks
  const int EGRID = 2048;          // same grid for count_bp & bucket_edges_p (same edge->partition map)

  // ---- graph preprocessing (shared by both layers)
  hipMemsetAsync(deg, 0, (size_t)n * 4, stream);
  hipMemsetAsync(cnt, 0, (size_t)NE * 4, stream);
  count_deg<<<2048, 256, 0, stream>>>(dst, deg, E);
  compute_dinv<<<nb, 256, 0, stream>>>(deg, dinv, n);
  scan_blocks<<<nb, 256, 0, stream>>>(deg, rowptr, bsum, n);
  scan_top<<<1, 512, 0, stream>>>(bsum, nb);
  add_offsets<<<nb, 256, 0, stream>>>(rowptr, bsum, n, E);
  count_bp<<<EGRID, 256, 0, stream>>>(dst, cnt, E, nbk);
  scan_bp<<<1, 256, 0, stream>>>(cnt, off, cur, nbk);
  bucket_edges_p<<<EGRID, 256, 0, stream>>>(src, dst, cur, pairs, E, nbk);
  local_fill<<<nbk, 256, 0, stream>>>(pairs, off, rowptr, colidx, n);

  const int pull_blocks = (n * 64 + 255) / 256;  // one wave per node

  // ---- layer 1
  gemm_nodes<128><<<gblocks, 256, 0, stream>>>(x, W1, dinv, B0);
  gather_agg<<<pull_blocks, 256, 0, stream>>>(rowptr, colidx, B0, dinv, b1, B1, n);

  // ---- layer 2
  gemm_nodes<64><<<gblocks, 256, 0, stream>>>(B1, W2, dinv, B0);
  gather_agg<<<pull_blocks, 256, 0, stream>>>(rowptr, colidx, B0, dinv, b2, B1, n);

  // ---- FC head
  gemm_fc<<<gblocks, 256, 0, stream>>>(B1, Wfc, bfc, out);
}

// Round 6
// 574.051 us; speedup vs baseline: 1.2154x; 1.2154x over previous
//
#include <hip/hip_runtime.h>

#define HID 64
#define SH 9          // log2(nodes per bucket)
#define BKN 512       // nodes per bucket
#define MAXB1 256     // max buckets supported (n <= 131072)
typedef unsigned int u32;

// ---------------------------------------------------------------- degree
__global__ __launch_bounds__(256) void count_deg(const int* __restrict__ dst,
                                                 int* __restrict__ deg, int E) {
  int i = blockIdx.x * 256 + threadIdx.x;
  const int stride = gridDim.x * 256;
  for (; i < E; i += stride) atomicAdd(&deg[dst[i]], 1);
}

__global__ __launch_bounds__(256) void compute_dinv(const int* __restrict__ deg,
                                                    float* __restrict__ dinv, int n) {
  const int i = blockIdx.x * 256 + threadIdx.x;
  if (i < n) dinv[i] = rsqrtf((float)(deg[i] + 1));  // +1 self-loop
}

// ---------------------------------------------------------------- scan (rowptr)
__global__ __launch_bounds__(256) void scan_blocks(const int* __restrict__ deg,
                                                   int* __restrict__ rowptr,
                                                   int* __restrict__ bsum, int n) {
  __shared__ int s[256];
  const int t = threadIdx.x;
  const int i = blockIdx.x * 256 + t;
  const int v = (i < n) ? deg[i] : 0;
  s[t] = v;
  __syncthreads();
  for (int off = 1; off < 256; off <<= 1) {
    const int u = (t >= off) ? s[t - off] : 0;
    __syncthreads();
    s[t] += u;
    __syncthreads();
  }
  if (i < n) rowptr[i] = s[t] - v;
  if (t == 255) bsum[blockIdx.x] = s[255];
}

__global__ __launch_bounds__(512) void scan_top(int* bsum, int nb) {
  __shared__ int s[512];
  const int t = threadIdx.x;
  const int v = (t < nb) ? bsum[t] : 0;
  s[t] = v;
  __syncthreads();
  for (int off = 1; off < 512; off <<= 1) {
    const int u = (t >= off) ? s[t - off] : 0;
    __syncthreads();
    s[t] += u;
    __syncthreads();
  }
  if (t < nb) bsum[t] = s[t] - v;
}

__global__ __launch_bounds__(256) void add_offsets(int* __restrict__ rowptr,
                                                   const int* __restrict__ bsum,
                                                   int n, int E) {
  const int i = blockIdx.x * 256 + threadIdx.x;
  if (i < n) rowptr[i] += bsum[blockIdx.x];
  if (i == 0) rowptr[n] = E;
}

// ---------------------------------------------------------------- bucket offsets (16-padded) + cursors
__global__ __launch_bounds__(256) void make_pb(const int* __restrict__ rowptr,
                                               int* __restrict__ pb_off,
                                               int* __restrict__ pb_cnt,
                                               int* __restrict__ cur,
                                               int n, int nbk) {
  __shared__ int s[256];
  const int t = threadIdx.x;
  int c = 0;
  if (t < nbk) {
    c = rowptr[min((t + 1) * BKN, n)] - rowptr[min(t * BKN, n)];
    pb_cnt[t] = c;
  }
  const int cp = (c + 15) & ~15;  // 16-aligned segment per bucket
  s[t] = cp;
  __syncthreads();
  for (int o = 1; o < 256; o <<= 1) {
    const int u = (t >= o) ? s[t - o] : 0;
    __syncthreads();
    s[t] += u;
    __syncthreads();
  }
  if (t < nbk) {
    pb_off[t] = s[t] - cp;
    cur[t * 16] = s[t] - cp;  // 64B-padded cursor
  }
}

// ---------------------------------------------------------------- LDS-staged bucketing
// packed u32: (dstLocal<<17) | src    (src < 2^17, dstLocal < 512)
// full groups of 16 flushed as one 64B line by a single thread: 1 global atomic
// per 16 edges, one writer XCD per line.
__global__ __launch_bounds__(256) void stage_bucket(const int* __restrict__ src,
                                                    const int* __restrict__ dst,
                                                    int* __restrict__ cur,
                                                    u32* __restrict__ pairs,
                                                    int E, int nbk) {
  __shared__ u32 stg[MAXB1 * 17];  // stride 17: conflict-free flusher reads
  __shared__ int lcnt[MAXB1];
  const int t = threadIdx.x;
  for (int b = t; b < nbk; b += 256) lcnt[b] = 0;
  __syncthreads();
  const int stride = gridDim.x * 256;
  const int rounds = (E + stride - 1) / stride;
  int i = blockIdx.x * 256 + t;
  int d = (i < E) ? dst[i] : -1;
  int sv = (i < E) ? src[i] : 0;
  for (int r = 0; r < rounds; ++r) {
    const int inext = i + stride;
    int dn = -1, sn = 0;
    if (inext < E) { dn = dst[inext]; sn = src[inext]; }  // prefetch next round
    if (d >= 0) {
      const int b = d >> SH;
      const u32 v = ((u32)(d & (BKN - 1)) << 17) | (u32)sv;
      const int sl = atomicAdd(&lcnt[b], 1);
      if (sl < 16) stg[b * 17 + sl] = v;
      else pairs[atomicAdd(&cur[b * 16], 1)] = v;  // rare overflow: direct write
    }
    __syncthreads();
    for (int b = t; b < nbk; b += 256) {  // flush full groups of 16
      if (lcnt[b] >= 16) {
        const int pos = atomicAdd(&cur[b * 16], 16);
#pragma unroll
        for (int k = 0; k < 16; ++k) pairs[pos + k] = stg[b * 17 + k];
        lcnt[b] = 0;
      }
    }
    __syncthreads();
    d = dn; sv = sn; i = inext;
  }
  for (int b = t; b < nbk; b += 256) {  // ragged tail
    const int rem = lcnt[b];
    if (rem > 0) {
      const int pos = atomicAdd(&cur[b * 16], rem);
      for (int k = 0; k < rem; ++k) pairs[pos + k] = stg[b * 17 + k];
    }
  }
}

// ---------------------------------------------------------------- exact CSR fill
// one block per (bucket, node-half): per-node LDS cursors, writes land in the
// half's contiguous ~32KB colidx window (single-XCD L2 resident)
__global__ __launch_bounds__(256) void local_fill2(const u32* __restrict__ pairs,
                                                   const int* __restrict__ pb_off,
                                                   const int* __restrict__ pb_cnt,
                                                   const int* __restrict__ rowptr,
                                                   int* __restrict__ colidx, int n) {
  __shared__ int lcur[BKN / 2];
  const int bkt = blockIdx.x >> 1;
  const int half = blockIdx.x & 1;
  const int nb0 = bkt * BKN + half * (BKN / 2);
  const int t = threadIdx.x;
  if (t < BKN / 2) {
    const int node = nb0 + t;
    lcur[t] = (node < n) ? rowptr[node] : 0;
  }
  __syncthreads();
  const int beg = pb_off[bkt], end = beg + pb_cnt[bkt];
  for (int e = beg + t; e < end; e += 256) {
    const u32 p = pairs[e];
    const int dloc = (int)(p >> 17);
    if ((dloc >> 8) == half) {
      const int pos = atomicAdd(&lcur[dloc & 255], 1);
      colidx[pos] = (int)(p & 0x1FFFF);
    }
  }
}

// ---------------------------------------------------------------- dense transform
// out[i, c] = dinv[i] * sum_k x[i,k] * W[k,c]
template <int K>
__global__ __launch_bounds__(256) void gemm_nodes(const float* __restrict__ x,
                                                  const float* __restrict__ W,
                                                  const float* __restrict__ dinv,
                                                  float* __restrict__ out) {
  __shared__ float Wl[K * 64];
  __shared__ float xl[16][K];
  const int tid = threadIdx.x;
  for (int i = tid; i < K * 16; i += 256)
    reinterpret_cast<float4*>(Wl)[i] = reinterpret_cast<const float4*>(W)[i];
  const int row0 = blockIdx.x * 16;
  for (int i = tid; i < 16 * (K / 4); i += 256) {
    const int r = i / (K / 4), q = i % (K / 4);
    reinterpret_cast<float4*>(&xl[r][0])[q] =
        reinterpret_cast<const float4*>(x + (size_t)(row0 + r) * K)[q];
  }
  __syncthreads();
  const int c = tid & 63;
  const int rbase = tid >> 6;
  for (int rr = rbase; rr < 16; rr += 4) {
    float acc = 0.f;
#pragma unroll
    for (int k = 0; k < K; k += 4) {
      const float4 xv = *reinterpret_cast<const float4*>(&xl[rr][k]);
      acc = fmaf(xv.x, Wl[(k + 0) * 64 + c], acc);
      acc = fmaf(xv.y, Wl[(k + 1) * 64 + c], acc);
      acc = fmaf(xv.z, Wl[(k + 2) * 64 + c], acc);
      acc = fmaf(xv.w, Wl[(k + 3) * 64 + c], acc);
    }
    const int grow = row0 + rr;
    out[(size_t)grow * 64 + c] = acc * dinv[grow];
  }
}

// ---------------------------------------------------------------- pull aggregation
// out[d,lane] = relu( dinv[d] * (sum_{s in N(d)} g[s,lane] + g[d,lane]) + b[lane] )
__global__ __launch_bounds__(256) void gather_agg(const int* __restrict__ rowptr,
                                                  const int* __restrict__ colidx,
                                                  const float* __restrict__ g,
                                                  const float* __restrict__ dinv,
                                                  const float* __restrict__ b,
                                                  float* __restrict__ out, int n) {
  const int lane = threadIdx.x & 63;
  const int node = (blockIdx.x * 256 + threadIdx.x) >> 6;
  if (node >= n) return;
  const int beg = rowptr[node];
  const int end = rowptr[node + 1];
  float acc = 0.f;
  int e = beg;
  for (; e + 4 <= end; e += 4) {  // 4-deep ILP to hide gather latency
    const int s0 = colidx[e + 0], s1 = colidx[e + 1];
    const int s2 = colidx[e + 2], s3 = colidx[e + 3];
    const float v0 = g[(size_t)s0 * HID + lane];
    const float v1 = g[(size_t)s1 * HID + lane];
    const float v2 = g[(size_t)s2 * HID + lane];
    const float v3 = g[(size_t)s3 * HID + lane];
    acc += (v0 + v1) + (v2 + v3);
  }
  for (; e < end; ++e) acc += g[(size_t)colidx[e] * HID + lane];
  acc += g[(size_t)node * HID + lane];  // self-loop
  const float r = fmaf(acc, dinv[node], b[lane]);
  out[(size_t)node * HID + lane] = fmaxf(r, 0.f);
}

// ---------------------------------------------------------------- final FC (64 -> 11)
__global__ __launch_bounds__(256) void gemm_fc(const float* __restrict__ h,
                                               const float* __restrict__ W,
                                               const float* __restrict__ b,
                                               float* __restrict__ out) {
  __shared__ float Wl[772];
  __shared__ float xl[16][68];
  const int tid = threadIdx.x;
  for (int i = tid; i < 772; i += 256) Wl[i] = 0.f;
  __syncthreads();
  for (int i = tid; i < 64 * 11; i += 256) Wl[(i / 11) * 12 + (i % 11)] = W[i];
  const int row0 = blockIdx.x * 16;
  for (int i = tid; i < 16 * 16; i += 256) {
    const int r = i >> 4, q = i & 15;
    const float4 v = reinterpret_cast<const float4*>(h + (size_t)(row0 + r) * 64)[q];
    xl[r][q * 4 + 0] = v.x; xl[r][q * 4 + 1] = v.y;
    xl[r][q * 4 + 2] = v.z; xl[r][q * 4 + 3] = v.w;
  }
  __syncthreads();
  const int r = tid >> 4, c = tid & 15;
  float acc = 0.f;
#pragma unroll
  for (int k = 0; k < 64; k += 4) {
    acc = fmaf(xl[r][k + 0], Wl[(k + 0) * 12 + c], acc);
    acc = fmaf(xl[r][k + 1], Wl[(k + 1) * 12 + c], acc);
    acc = fmaf(xl[r][k + 2], Wl[(k + 2) * 12 + c], acc);
    acc = fmaf(xl[r][k + 3], Wl[(k + 3) * 12 + c], acc);
  }
  if (c < 11) out[(size_t)(row0 + r) * 11 + c] = acc + b[c];
}

// ---------------------------------------------------------------- launch
extern "C" void kernel_launch(void* const* d_in, const int* in_sizes, int n_in,
                              void* d_out, int out_size, void* d_ws, size_t ws_size,
                              hipStream_t stream) {
  const float* x   = (const float*)d_in[0];
  const int*   ei  = (const int*)d_in[1];   // [2, E] int32
  const float* W1  = (const float*)d_in[2];
  const float* b1  = (const float*)d_in[3];
  const float* W2  = (const float*)d_in[4];
  const float* b2  = (const float*)d_in[5];
  const float* Wfc = (const float*)d_in[6];
  const float* bfc = (const float*)d_in[7];
  float* out = (float*)d_out;

  const int n = in_sizes[0] / 128;  // 100000
  const int E = in_sizes[1] / 2;    // 3200000
  const int* src = ei;
  const int* dst = ei + E;
  const int nbk = (n + BKN - 1) >> SH;  // 196 buckets

  char* ws = (char*)d_ws;
  size_t o = 0;
  auto alloc = [&](size_t bytes) {
    char* p = ws + o;
    o += (bytes + 255) & ~(size_t)255;
    return p;
  };
  int*   deg    = (int*)  alloc((size_t)n * 4);
  float* dinv   = (float*)alloc((size_t)n * 4);
  int*   rowptr = (int*)  alloc((size_t)(n + 1) * 4);
  int*   bsum   = (int*)  alloc(512 * 4);
  int*   pb_off = (int*)  alloc(MAXB1 * 4);
  int*   pb_cnt = (int*)  alloc(MAXB1 * 4);
  int*   cur    = (int*)  alloc(MAXB1 * 16 * 4);          // 64B-padded cursors
  u32*   pairs  = (u32*)  alloc(((size_t)E + 16 * MAXB1) * 4);
  int*   colidx = (int*)  alloc((size_t)E * 4);
  float* B0     = (float*)alloc((size_t)n * HID * 4);
  float* B1     = (float*)alloc((size_t)n * HID * 4);
  if (o > ws_size) return;

  const int nb = (n + 255) / 256;  // 391 scan blocks
  const int gblocks = n / 16;      // 6250 gemm blocks

  // ---- graph preprocessing (shared by both layers)
  hipMemsetAsync(deg, 0, (size_t)n * 4, stream);
  count_deg<<<2048, 256, 0, stream>>>(dst, deg, E);
  compute_dinv<<<nb, 256, 0, stream>>>(deg, dinv, n);
  scan_blocks<<<nb, 256, 0, stream>>>(deg, rowptr, bsum, n);
  scan_top<<<1, 512, 0, stream>>>(bsum, nb);
  add_offsets<<<nb, 256, 0, stream>>>(rowptr, bsum, n, E);
  make_pb<<<1, 256, 0, stream>>>(rowptr, pb_off, pb_cnt, cur, n, nbk);
  stage_bucket<<<256, 256, 0, stream>>>(src, dst, cur, pairs, E, nbk);
  local_fill2<<<nbk * 2, 256, 0, stream>>>(pairs, pb_off, pb_cnt, rowptr, colidx, n);

  const int pull_blocks = (n * 64 + 255) / 256;  // one wave per node

  // ---- layer 1
  gemm_nodes<128><<<gblocks, 256, 0, stream>>>(x, W1, dinv, B0);
  gather_agg<<<pull_blocks, 256, 0, stream>>>(rowptr, colidx, B0, dinv, b1, B1, n);

  // ---- layer 2
  gemm_nodes<64><<<gblocks, 256, 0, stream>>>(B1, W2, dinv, B0);
  gather_agg<<<pull_blocks, 256, 0, stream>>>(rowptr, colidx, B0, dinv, b2, B1, n);

  // ---- FC head
  gemm_fc<<<gblocks, 256, 0, stream>>>(B1, Wfc, bfc, out);
}

// Round 7
// 477.344 us; speedup vs baseline: 1.4617x; 1.2026x over previous
//
#include <hip/hip_runtime.h>

#define HID 64
#define SH 9          // log2(nodes per bucket)
#define BKN 512       // nodes per bucket
#define MAXB1 256     // max buckets supported (n <= 131072)
typedef unsigned int u32;

// ---------------------------------------------------------------- bucket-level histogram
// LDS-staged: 196 hot counters per block, one global atomic per (block,bucket)
__global__ __launch_bounds__(256) void count_bkt(const int* __restrict__ dst,
                                                 int* __restrict__ cnt,
                                                 int E, int nbk) {
  __shared__ int lc[MAXB1];
  const int t = threadIdx.x;
  for (int b = t; b < nbk; b += 256) lc[b] = 0;
  __syncthreads();
  const int stride = gridDim.x * 256;
  for (int i = blockIdx.x * 256 + t; i < E; i += stride)
    atomicAdd(&lc[dst[i] >> SH], 1);
  __syncthreads();
  for (int b = t; b < nbk; b += 256)
    if (lc[b]) atomicAdd(&cnt[b], lc[b]);
}

// ---------------------------------------------------------------- scan bucket counts
// pb_off = 16-padded exclusive scan of cnt; also inits 64B-padded cursors
__global__ __launch_bounds__(256) void scan_bkt(const int* __restrict__ cnt,
                                                int* __restrict__ pb_off,
                                                int* __restrict__ cur, int nbk) {
  __shared__ int s[256];
  const int t = threadIdx.x;
  const int c = (t < nbk) ? cnt[t] : 0;
  const int cp = (c + 15) & ~15;  // 16-aligned segment
  s[t] = cp;
  __syncthreads();
  for (int o = 1; o < 256; o <<= 1) {
    const int u = (t >= o) ? s[t - o] : 0;
    __syncthreads();
    s[t] += u;
    __syncthreads();
  }
  if (t < nbk) {
    pb_off[t] = s[t] - cp;
    cur[t * 16] = s[t] - cp;
  }
}

// ---------------------------------------------------------------- LDS-staged bucketing
// packed u32: (dstLocal<<17) | src    (src < 2^17, dstLocal < 512)
// full groups of 16 flushed as one 64B line: 1 global atomic per 16 edges
__global__ __launch_bounds__(256) void stage_bucket(const int* __restrict__ src,
                                                    const int* __restrict__ dst,
                                                    int* __restrict__ cur,
                                                    u32* __restrict__ pairs,
                                                    int E, int nbk) {
  __shared__ u32 stg[MAXB1 * 17];  // stride 17: conflict-free flusher reads
  __shared__ int lcnt[MAXB1];
  const int t = threadIdx.x;
  for (int b = t; b < nbk; b += 256) lcnt[b] = 0;
  __syncthreads();
  const int stride = gridDim.x * 256;
  const int rounds = (E + stride - 1) / stride;
  int i = blockIdx.x * 256 + t;
  int d = (i < E) ? dst[i] : -1;
  int sv = (i < E) ? src[i] : 0;
  for (int r = 0; r < rounds; ++r) {
    const int inext = i + stride;
    int dn = -1, sn = 0;
    if (inext < E) { dn = dst[inext]; sn = src[inext]; }  // prefetch next round
    if (d >= 0) {
      const int b = d >> SH;
      const u32 v = ((u32)(d & (BKN - 1)) << 17) | (u32)sv;
      const int sl = atomicAdd(&lcnt[b], 1);
      if (sl < 16) stg[b * 17 + sl] = v;
      else pairs[atomicAdd(&cur[b * 16], 1)] = v;  // rare overflow: direct write
    }
    __syncthreads();
    for (int b = t; b < nbk; b += 256) {  // flush full groups of 16
      if (lcnt[b] >= 16) {
        const int pos = atomicAdd(&cur[b * 16], 16);
#pragma unroll
        for (int k = 0; k < 16; ++k) pairs[pos + k] = stg[b * 17 + k];
        lcnt[b] = 0;
      }
    }
    __syncthreads();
    d = dn; sv = sn; i = inext;
  }
  for (int b = t; b < nbk; b += 256) {  // ragged tail
    const int rem = lcnt[b];
    if (rem > 0) {
      const int pos = atomicAdd(&cur[b * 16], rem);
      for (int k = 0; k < rem; ++k) pairs[pos + k] = stg[b * 17 + k];
    }
  }
}

// ---------------------------------------------------------------- per-node degree + dinv
// one block per bucket: count dstLocal in LDS from the bucket's pairs (no
// global atomics), write deg + dinv coalesced
__global__ __launch_bounds__(256) void bucket_deg(const u32* __restrict__ pairs,
                                                  const int* __restrict__ pb_off,
                                                  const int* __restrict__ cnt,
                                                  int* __restrict__ deg,
                                                  float* __restrict__ dinv, int n) {
  __shared__ int ldeg[BKN];
  const int bkt = blockIdx.x;
  const int t = threadIdx.x;
  for (int i = t; i < BKN; i += 256) ldeg[i] = 0;
  __syncthreads();
  const int beg = pb_off[bkt], end = beg + cnt[bkt];
  for (int e = beg + t; e < end; e += 256) atomicAdd(&ldeg[pairs[e] >> 17], 1);
  __syncthreads();
  const int base = bkt * BKN;
  for (int i = t; i < BKN; i += 256) {
    const int node = base + i;
    if (node < n) {
      const int dg = ldeg[i];
      deg[node] = dg;
      dinv[node] = rsqrtf((float)(dg + 1));  // +1 self-loop
    }
  }
}

// ---------------------------------------------------------------- scan (rowptr)
__global__ __launch_bounds__(256) void scan_blocks(const int* __restrict__ deg,
                                                   int* __restrict__ rowptr,
                                                   int* __restrict__ bsum, int n) {
  __shared__ int s[256];
  const int t = threadIdx.x;
  const int i = blockIdx.x * 256 + t;
  const int v = (i < n) ? deg[i] : 0;
  s[t] = v;
  __syncthreads();
  for (int off = 1; off < 256; off <<= 1) {
    const int u = (t >= off) ? s[t - off] : 0;
    __syncthreads();
    s[t] += u;
    __syncthreads();
  }
  if (i < n) rowptr[i] = s[t] - v;
  if (t == 255) bsum[blockIdx.x] = s[255];
}

__global__ __launch_bounds__(512) void scan_top(int* bsum, int nb) {
  __shared__ int s[512];
  const int t = threadIdx.x;
  const int v = (t < nb) ? bsum[t] : 0;
  s[t] = v;
  __syncthreads();
  for (int off = 1; off < 512; off <<= 1) {
    const int u = (t >= off) ? s[t - off] : 0;
    __syncthreads();
    s[t] += u;
    __syncthreads();
  }
  if (t < nb) bsum[t] = s[t] - v;
}

__global__ __launch_bounds__(256) void add_offsets(int* __restrict__ rowptr,
                                                   const int* __restrict__ bsum,
                                                   int n, int E) {
  const int i = blockIdx.x * 256 + threadIdx.x;
  if (i < n) rowptr[i] += bsum[blockIdx.x];
  if (i == 0) rowptr[n] = E;
}

// ---------------------------------------------------------------- exact CSR fill
// one block per (bucket, node-half): per-node LDS cursors, writes land in the
// half's contiguous ~32KB colidx window
__global__ __launch_bounds__(256) void local_fill2(const u32* __restrict__ pairs,
                                                   const int* __restrict__ pb_off,
                                                   const int* __restrict__ pb_cnt,
                                                   const int* __restrict__ rowptr,
                                                   int* __restrict__ colidx, int n) {
  __shared__ int lcur[BKN / 2];
  const int bkt = blockIdx.x >> 1;
  const int half = blockIdx.x & 1;
  const int nb0 = bkt * BKN + half * (BKN / 2);
  const int t = threadIdx.x;
  if (t < BKN / 2) {
    const int node = nb0 + t;
    lcur[t] = (node < n) ? rowptr[node] : 0;
  }
  __syncthreads();
  const int beg = pb_off[bkt], end = beg + pb_cnt[bkt];
  for (int e = beg + t; e < end; e += 256) {
    const u32 p = pairs[e];
    const int dloc = (int)(p >> 17);
    if ((dloc >> 8) == half) {
      const int pos = atomicAdd(&lcur[dloc & 255], 1);
      colidx[pos] = (int)(p & 0x1FFFF);
    }
  }
}

// ---------------------------------------------------------------- dense transform
// out[i, c] = dinv[i] * sum_k x[i,k] * W[k,c]
template <int K>
__global__ __launch_bounds__(256) void gemm_nodes(const float* __restrict__ x,
                                                  const float* __restrict__ W,
                                                  const float* __restrict__ dinv,
                                                  float* __restrict__ out) {
  __shared__ float Wl[K * 64];
  __shared__ float xl[16][K];
  const int tid = threadIdx.x;
  for (int i = tid; i < K * 16; i += 256)
    reinterpret_cast<float4*>(Wl)[i] = reinterpret_cast<const float4*>(W)[i];
  const int row0 = blockIdx.x * 16;
  for (int i = tid; i < 16 * (K / 4); i += 256) {
    const int r = i / (K / 4), q = i % (K / 4);
    reinterpret_cast<float4*>(&xl[r][0])[q] =
        reinterpret_cast<const float4*>(x + (size_t)(row0 + r) * K)[q];
  }
  __syncthreads();
  const int c = tid & 63;
  const int rbase = tid >> 6;
  for (int rr = rbase; rr < 16; rr += 4) {
    float acc = 0.f;
#pragma unroll
    for (int k = 0; k < K; k += 4) {
      const float4 xv = *reinterpret_cast<const float4*>(&xl[rr][k]);
      acc = fmaf(xv.x, Wl[(k + 0) * 64 + c], acc);
      acc = fmaf(xv.y, Wl[(k + 1) * 64 + c], acc);
      acc = fmaf(xv.z, Wl[(k + 2) * 64 + c], acc);
      acc = fmaf(xv.w, Wl[(k + 3) * 64 + c], acc);
    }
    const int grow = row0 + rr;
    out[(size_t)grow * 64 + c] = acc * dinv[grow];
  }
}

// ---------------------------------------------------------------- pull aggregation
// out[d,lane] = relu( dinv[d] * (sum_{s in N(d)} g[s,lane] + g[d,lane]) + b[lane] )
__global__ __launch_bounds__(256) void gather_agg(const int* __restrict__ rowptr,
                                                  const int* __restrict__ colidx,
                                                  const float* __restrict__ g,
                                                  const float* __restrict__ dinv,
                                                  const float* __restrict__ b,
                                                  float* __restrict__ out, int n) {
  const int lane = threadIdx.x & 63;
  const int node = (blockIdx.x * 256 + threadIdx.x) >> 6;
  if (node >= n) return;
  const int beg = rowptr[node];
  const int end = rowptr[node + 1];
  float acc = 0.f;
  int e = beg;
  for (; e + 4 <= end; e += 4) {  // 4-deep ILP to hide gather latency
    const int s0 = colidx[e + 0], s1 = colidx[e + 1];
    const int s2 = colidx[e + 2], s3 = colidx[e + 3];
    const float v0 = g[(size_t)s0 * HID + lane];
    const float v1 = g[(size_t)s1 * HID + lane];
    const float v2 = g[(size_t)s2 * HID + lane];
    const float v3 = g[(size_t)s3 * HID + lane];
    acc += (v0 + v1) + (v2 + v3);
  }
  for (; e < end; ++e) acc += g[(size_t)colidx[e] * HID + lane];
  acc += g[(size_t)node * HID + lane];  // self-loop
  const float r = fmaf(acc, dinv[node], b[lane]);
  out[(size_t)node * HID + lane] = fmaxf(r, 0.f);
}

// ---------------------------------------------------------------- final FC (64 -> 11)
__global__ __launch_bounds__(256) void gemm_fc(const float* __restrict__ h,
                                               const float* __restrict__ W,
                                               const float* __restrict__ b,
                                               float* __restrict__ out) {
  __shared__ float Wl[772];
  __shared__ float xl[16][68];
  const int tid = threadIdx.x;
  for (int i = tid; i < 772; i += 256) Wl[i] = 0.f;
  __syncthreads();
  for (int i = tid; i < 64 * 11; i += 256) Wl[(i / 11) * 12 + (i % 11)] = W[i];
  const int row0 = blockIdx.x * 16;
  for (int i = tid; i < 16 * 16; i += 256) {
    const int r = i >> 4, q = i & 15;
    const float4 v = reinterpret_cast<const float4*>(h + (size_t)(row0 + r) * 64)[q];
    xl[r][q * 4 + 0] = v.x; xl[r][q * 4 + 1] = v.y;
    xl[r][q * 4 + 2] = v.z; xl[r][q * 4 + 3] = v.w;
  }
  __syncthreads();
  const int r = tid >> 4, c = tid & 15;
  float acc = 0.f;
#pragma unroll
  for (int k = 0; k < 64; k += 4) {
    acc = fmaf(xl[r][k + 0], Wl[(k + 0) * 12 + c], acc);
    acc = fmaf(xl[r][k + 1], Wl[(k + 1) * 12 + c], acc);
    acc = fmaf(xl[r][k + 2], Wl[(k + 2) * 12 + c], acc);
    acc = fmaf(xl[r][k + 3], Wl[(k + 3) * 12 + c], acc);
  }
  if (c < 11) out[(size_t)(row0 + r) * 11 + c] = acc + b[c];
}

// ---------------------------------------------------------------- launch
extern "C" void kernel_launch(void* const* d_in, const int* in_sizes, int n_in,
                              void* d_out, int out_size, void* d_ws, size_t ws_size,
                              hipStream_t stream) {
  const float* x   = (const float*)d_in[0];
  const int*   ei  = (const int*)d_in[1];   // [2, E] int32
  const float* W1  = (const float*)d_in[2];
  const float* b1  = (const float*)d_in[3];
  const float* W2  = (const float*)d_in[4];
  const float* b2  = (const float*)d_in[5];
  const float* Wfc = (const float*)d_in[6];
  const float* bfc = (const float*)d_in[7];
  float* out = (float*)d_out;

  const int n = in_sizes[0] / 128;  // 100000
  const int E = in_sizes[1] / 2;    // 3200000
  const int* src = ei;
  const int* dst = ei + E;
  const int nbk = (n + BKN - 1) >> SH;  // 196 buckets

  char* ws = (char*)d_ws;
  size_t o = 0;
  auto alloc = [&](size_t bytes) {
    char* p = ws + o;
    o += (bytes + 255) & ~(size_t)255;
    return p;
  };
  int*   deg    = (int*)  alloc((size_t)n * 4);
  float* dinv   = (float*)alloc((size_t)n * 4);
  int*   rowptr = (int*)  alloc((size_t)(n + 1) * 4);
  int*   bsum   = (int*)  alloc(512 * 4);
  int*   cnt    = (int*)  alloc(MAXB1 * 4);
  int*   pb_off = (int*)  alloc(MAXB1 * 4);
  int*   cur    = (int*)  alloc(MAXB1 * 16 * 4);          // 64B-padded cursors
  u32*   pairs  = (u32*)  alloc(((size_t)E + 16 * MAXB1) * 4);
  int*   colidx = (int*)  alloc((size_t)E * 4);
  float* B0     = (float*)alloc((size_t)n * HID * 4);
  float* B1     = (float*)alloc((size_t)n * HID * 4);
  if (o > ws_size) return;

  const int nb = (n + 255) / 256;  // 391 scan blocks
  const int gblocks = n / 16;      // 6250 gemm blocks

  // ---- graph preprocessing (shared by both layers)
  hipMemsetAsync(cnt, 0, MAXB1 * 4, stream);
  count_bkt<<<256, 256, 0, stream>>>(dst, cnt, E, nbk);
  scan_bkt<<<1, 256, 0, stream>>>(cnt, pb_off, cur, nbk);
  stage_bucket<<<256, 256, 0, stream>>>(src, dst, cur, pairs, E, nbk);
  bucket_deg<<<nbk, 256, 0, stream>>>(pairs, pb_off, cnt, deg, dinv, n);
  scan_blocks<<<nb, 256, 0, stream>>>(deg, rowptr, bsum, n);
  scan_top<<<1, 512, 0, stream>>>(bsum, nb);
  add_offsets<<<nb, 256, 0, stream>>>(rowptr, bsum, n, E);
  local_fill2<<<nbk * 2, 256, 0, stream>>>(pairs, pb_off, cnt, rowptr, colidx, n);

  const int pull_blocks = (n * 64 + 255) / 256;  // one wave per node

  // ---- layer 1
  gemm_nodes<128><<<gblocks, 256, 0, stream>>>(x, W1, dinv, B0);
  gather_agg<<<pull_blocks, 256, 0, stream>>>(rowptr, colidx, B0, dinv, b1, B1, n);

  // ---- layer 2
  gemm_nodes<64><<<gblocks, 256, 0, stream>>>(B1, W2, dinv, B0);
  gather_agg<<<pull_blocks, 256, 0, stream>>>(rowptr, colidx, B0, dinv, b2, B1, n);

  // ---- FC head
  gemm_fc<<<gblocks, 256, 0, stream>>>(B1, Wfc, bfc, out);
}

// Round 8
// 444.231 us; speedup vs baseline: 1.5706x; 1.0745x over previous
//
#include <hip/hip_runtime.h>
#include <hip/hip_fp16.h>

#define HID 64
#define SH 9          // log2(nodes per bucket)
#define BKN 512       // nodes per bucket
#define MAXB1 256     // max buckets supported (n <= 131072)
typedef unsigned int u32;

// ---------------------------------------------------------------- bucket-level histogram
__global__ __launch_bounds__(256) void count_bkt(const int* __restrict__ dst,
                                                 int* __restrict__ cnt,
                                                 int E, int nbk) {
  __shared__ int lc[MAXB1];
  const int t = threadIdx.x;
  for (int b = t; b < nbk; b += 256) lc[b] = 0;
  __syncthreads();
  const int stride = gridDim.x * 256;
  for (int i = blockIdx.x * 256 + t; i < E; i += stride)
    atomicAdd(&lc[dst[i] >> SH], 1);
  __syncthreads();
  for (int b = t; b < nbk; b += 256)
    if (lc[b]) atomicAdd(&cnt[b], lc[b]);
}

// ---------------------------------------------------------------- scan bucket counts
__global__ __launch_bounds__(256) void scan_bkt(const int* __restrict__ cnt,
                                                int* __restrict__ pb_off,
                                                int* __restrict__ cur, int nbk) {
  __shared__ int s[256];
  const int t = threadIdx.x;
  const int c = (t < nbk) ? cnt[t] : 0;
  const int cp = (c + 15) & ~15;  // 16-aligned segment
  s[t] = cp;
  __syncthreads();
  for (int o = 1; o < 256; o <<= 1) {
    const int u = (t >= o) ? s[t - o] : 0;
    __syncthreads();
    s[t] += u;
    __syncthreads();
  }
  if (t < nbk) {
    pb_off[t] = s[t] - cp;
    cur[t * 16] = s[t] - cp;
  }
}

// ---------------------------------------------------------------- LDS-staged bucketing
// packed u32: (dstLocal<<17) | src    (src < 2^17, dstLocal < 512)
__global__ __launch_bounds__(256) void stage_bucket(const int* __restrict__ src,
                                                    const int* __restrict__ dst,
                                                    int* __restrict__ cur,
                                                    u32* __restrict__ pairs,
                                                    int E, int nbk) {
  __shared__ u32 stg[MAXB1 * 17];  // stride 17: conflict-free flusher reads
  __shared__ int lcnt[MAXB1];
  const int t = threadIdx.x;
  for (int b = t; b < nbk; b += 256) lcnt[b] = 0;
  __syncthreads();
  const int stride = gridDim.x * 256;
  const int rounds = (E + stride - 1) / stride;
  int i = blockIdx.x * 256 + t;
  int d = (i < E) ? dst[i] : -1;
  int sv = (i < E) ? src[i] : 0;
  for (int r = 0; r < rounds; ++r) {
    const int inext = i + stride;
    int dn = -1, sn = 0;
    if (inext < E) { dn = dst[inext]; sn = src[inext]; }  // prefetch next round
    if (d >= 0) {
      const int b = d >> SH;
      const u32 v = ((u32)(d & (BKN - 1)) << 17) | (u32)sv;
      const int sl = atomicAdd(&lcnt[b], 1);
      if (sl < 16) stg[b * 17 + sl] = v;
      else pairs[atomicAdd(&cur[b * 16], 1)] = v;  // rare overflow: direct write
    }
    __syncthreads();
    for (int b = t; b < nbk; b += 256) {  // flush full groups of 16
      if (lcnt[b] >= 16) {
        const int pos = atomicAdd(&cur[b * 16], 16);
#pragma unroll
        for (int k = 0; k < 16; ++k) pairs[pos + k] = stg[b * 17 + k];
        lcnt[b] = 0;
      }
    }
    __syncthreads();
    d = dn; sv = sn; i = inext;
  }
  for (int b = t; b < nbk; b += 256) {  // ragged tail
    const int rem = lcnt[b];
    if (rem > 0) {
      const int pos = atomicAdd(&cur[b * 16], rem);
      for (int k = 0; k < rem; ++k) pairs[pos + k] = stg[b * 17 + k];
    }
  }
}

// ---------------------------------------------------------------- per-node degree + dinv
__global__ __launch_bounds__(256) void bucket_deg(const u32* __restrict__ pairs,
                                                  const int* __restrict__ pb_off,
                                                  const int* __restrict__ cnt,
                                                  int* __restrict__ deg,
                                                  float* __restrict__ dinv, int n) {
  __shared__ int ldeg[BKN];
  const int bkt = blockIdx.x;
  const int t = threadIdx.x;
  for (int i = t; i < BKN; i += 256) ldeg[i] = 0;
  __syncthreads();
  const int beg = pb_off[bkt], end = beg + cnt[bkt];
  for (int e = beg + t; e < end; e += 256) atomicAdd(&ldeg[pairs[e] >> 17], 1);
  __syncthreads();
  const int base = bkt * BKN;
  for (int i = t; i < BKN; i += 256) {
    const int node = base + i;
    if (node < n) {
      const int dg = ldeg[i];
      deg[node] = dg;
      dinv[node] = rsqrtf((float)(dg + 1));  // +1 self-loop
    }
  }
}

// ---------------------------------------------------------------- scan (rowptr)
__global__ __launch_bounds__(256) void scan_blocks(const int* __restrict__ deg,
                                                   int* __restrict__ rowptr,
                                                   int* __restrict__ bsum, int n) {
  __shared__ int s[256];
  const int t = threadIdx.x;
  const int i = blockIdx.x * 256 + t;
  const int v = (i < n) ? deg[i] : 0;
  s[t] = v;
  __syncthreads();
  for (int off = 1; off < 256; off <<= 1) {
    const int u = (t >= off) ? s[t - off] : 0;
    __syncthreads();
    s[t] += u;
    __syncthreads();
  }
  if (i < n) rowptr[i] = s[t] - v;
  if (t == 255) bsum[blockIdx.x] = s[255];
}

__global__ __launch_bounds__(512) void scan_top(int* bsum, int nb) {
  __shared__ int s[512];
  const int t = threadIdx.x;
  const int v = (t < nb) ? bsum[t] : 0;
  s[t] = v;
  __syncthreads();
  for (int off = 1; off < 512; off <<= 1) {
    const int u = (t >= off) ? s[t - off] : 0;
    __syncthreads();
    s[t] += u;
    __syncthreads();
  }
  if (t < nb) bsum[t] = s[t] - v;
}

__global__ __launch_bounds__(256) void add_offsets(int* __restrict__ rowptr,
                                                   const int* __restrict__ bsum,
                                                   int n, int E) {
  const int i = blockIdx.x * 256 + threadIdx.x;
  if (i < n) rowptr[i] += bsum[blockIdx.x];
  if (i == 0) rowptr[n] = E;
}

// ---------------------------------------------------------------- exact CSR fill
__global__ __launch_bounds__(256) void local_fill2(const u32* __restrict__ pairs,
                                                   const int* __restrict__ pb_off,
                                                   const int* __restrict__ pb_cnt,
                                                   const int* __restrict__ rowptr,
                                                   int* __restrict__ colidx, int n) {
  __shared__ int lcur[BKN / 2];
  const int bkt = blockIdx.x >> 1;
  const int half = blockIdx.x & 1;
  const int nb0 = bkt * BKN + half * (BKN / 2);
  const int t = threadIdx.x;
  if (t < BKN / 2) {
    const int node = nb0 + t;
    lcur[t] = (node < n) ? rowptr[node] : 0;
  }
  __syncthreads();
  const int beg = pb_off[bkt], end = beg + pb_cnt[bkt];
  for (int e = beg + t; e < end; e += 256) {
    const u32 p = pairs[e];
    const int dloc = (int)(p >> 17);
    if ((dloc >> 8) == half) {
      const int pos = atomicAdd(&lcur[dloc & 255], 1);
      colidx[pos] = (int)(p & 0x1FFFF);
    }
  }
}

// ---------------------------------------------------------------- dense transform
// g[i, c] = fp16( dinv[i] * sum_k x[i,k] * W[k,c] )   -- halves gather bytes
template <int K>
__global__ __launch_bounds__(256) void gemm_nodes(const float* __restrict__ x,
                                                  const float* __restrict__ W,
                                                  const float* __restrict__ dinv,
                                                  __half* __restrict__ out) {
  __shared__ float Wl[K * 64];
  __shared__ float xl[16][K];
  const int tid = threadIdx.x;
  for (int i = tid; i < K * 16; i += 256)
    reinterpret_cast<float4*>(Wl)[i] = reinterpret_cast<const float4*>(W)[i];
  const int row0 = blockIdx.x * 16;
  for (int i = tid; i < 16 * (K / 4); i += 256) {
    const int r = i / (K / 4), q = i % (K / 4);
    reinterpret_cast<float4*>(&xl[r][0])[q] =
        reinterpret_cast<const float4*>(x + (size_t)(row0 + r) * K)[q];
  }
  __syncthreads();
  const int c = tid & 63;
  const int rbase = tid >> 6;
  for (int rr = rbase; rr < 16; rr += 4) {
    float acc = 0.f;
#pragma unroll
    for (int k = 0; k < K; k += 4) {
      const float4 xv = *reinterpret_cast<const float4*>(&xl[rr][k]);
      acc = fmaf(xv.x, Wl[(k + 0) * 64 + c], acc);
      acc = fmaf(xv.y, Wl[(k + 1) * 64 + c], acc);
      acc = fmaf(xv.z, Wl[(k + 2) * 64 + c], acc);
      acc = fmaf(xv.w, Wl[(k + 3) * 64 + c], acc);
    }
    const int grow = row0 + rr;
    out[(size_t)grow * 64 + c] = __float2half(acc * dinv[grow]);
  }
}

// ---------------------------------------------------------------- pull aggregation (fp16 gather)
// out[d,lane] = relu( dinv[d] * (sum_{s in N(d)} g[s,lane] + g[d,lane]) + b[lane] )
__global__ __launch_bounds__(256) void gather_agg(const int* __restrict__ rowptr,
                                                  const int* __restrict__ colidx,
                                                  const __half* __restrict__ g,
                                                  const float* __restrict__ dinv,
                                                  const float* __restrict__ b,
                                                  float* __restrict__ out, int n) {
  const int lane = threadIdx.x & 63;
  const int node = (blockIdx.x * 256 + threadIdx.x) >> 6;
  if (node >= n) return;
  const int beg = rowptr[node];
  const int end = rowptr[node + 1];
  float acc = 0.f;
  int e = beg;
  for (; e + 4 <= end; e += 4) {  // 4-deep ILP to hide gather latency
    const int s0 = colidx[e + 0], s1 = colidx[e + 1];
    const int s2 = colidx[e + 2], s3 = colidx[e + 3];
    const float v0 = __half2float(g[(size_t)s0 * HID + lane]);
    const float v1 = __half2float(g[(size_t)s1 * HID + lane]);
    const float v2 = __half2float(g[(size_t)s2 * HID + lane]);
    const float v3 = __half2float(g[(size_t)s3 * HID + lane]);
    acc += (v0 + v1) + (v2 + v3);
  }
  for (; e < end; ++e) acc += __half2float(g[(size_t)colidx[e] * HID + lane]);
  acc += __half2float(g[(size_t)node * HID + lane]);  // self-loop
  const float r = fmaf(acc, dinv[node], b[lane]);
  out[(size_t)node * HID + lane] = fmaxf(r, 0.f);
}

// ---------------------------------------------------------------- final FC (64 -> 11)
__global__ __launch_bounds__(256) void gemm_fc(const float* __restrict__ h,
                                               const float* __restrict__ W,
                                               const float* __restrict__ b,
                                               float* __restrict__ out) {
  __shared__ float Wl[772];
  __shared__ float xl[16][68];
  const int tid = threadIdx.x;
  for (int i = tid; i < 772; i += 256) Wl[i] = 0.f;
  __syncthreads();
  for (int i = tid; i < 64 * 11; i += 256) Wl[(i / 11) * 12 + (i % 11)] = W[i];
  const int row0 = blockIdx.x * 16;
  for (int i = tid; i < 16 * 16; i += 256) {
    const int r = i >> 4, q = i & 15;
    const float4 v = reinterpret_cast<const float4*>(h + (size_t)(row0 + r) * 64)[q];
    xl[r][q * 4 + 0] = v.x; xl[r][q * 4 + 1] = v.y;
    xl[r][q * 4 + 2] = v.z; xl[r][q * 4 + 3] = v.w;
  }
  __syncthreads();
  const int r = tid >> 4, c = tid & 15;
  float acc = 0.f;
#pragma unroll
  for (int k = 0; k < 64; k += 4) {
    acc = fmaf(xl[r][k + 0], Wl[(k + 0) * 12 + c], acc);
    acc = fmaf(xl[r][k + 1], Wl[(k + 1) * 12 + c], acc);
    acc = fmaf(xl[r][k + 2], Wl[(k + 2) * 12 + c], acc);
    acc = fmaf(xl[r][k + 3], Wl[(k + 3) * 12 + c], acc);
  }
  if (c < 11) out[(size_t)(row0 + r) * 11 + c] = acc + b[c];
}

// ---------------------------------------------------------------- launch
extern "C" void kernel_launch(void* const* d_in, const int* in_sizes, int n_in,
                              void* d_out, int out_size, void* d_ws, size_t ws_size,
                              hipStream_t stream) {
  const float* x   = (const float*)d_in[0];
  const int*   ei  = (const int*)d_in[1];   // [2, E] int32
  const float* W1  = (const float*)d_in[2];
  const float* b1  = (const float*)d_in[3];
  const float* W2  = (const float*)d_in[4];
  const float* b2  = (const float*)d_in[5];
  const float* Wfc = (const float*)d_in[6];
  const float* bfc = (const float*)d_in[7];
  float* out = (float*)d_out;

  const int n = in_sizes[0] / 128;  // 100000
  const int E = in_sizes[1] / 2;    // 3200000
  const int* src = ei;
  const int* dst = ei + E;
  const int nbk = (n + BKN - 1) >> SH;  // 196 buckets

  char* ws = (char*)d_ws;
  size_t o = 0;
  auto alloc = [&](size_t bytes) {
    char* p = ws + o;
    o += (bytes + 255) & ~(size_t)255;
    return p;
  };
  int*    deg    = (int*)   alloc((size_t)n * 4);
  float*  dinv   = (float*) alloc((size_t)n * 4);
  int*    rowptr = (int*)   alloc((size_t)(n + 1) * 4);
  int*    bsum   = (int*)   alloc(512 * 4);
  int*    cnt    = (int*)   alloc(MAXB1 * 4);
  int*    pb_off = (int*)   alloc(MAXB1 * 4);
  int*    cur    = (int*)   alloc(MAXB1 * 16 * 4);          // 64B-padded cursors
  u32*    pairs  = (u32*)   alloc(((size_t)E + 16 * MAXB1) * 4);
  int*    colidx = (int*)   alloc((size_t)E * 4);
  __half* B0h    = (__half*)alloc((size_t)n * HID * 2);     // g in fp16
  float*  B1     = (float*) alloc((size_t)n * HID * 4);     // layer output fp32
  if (o > ws_size) return;

  const int nb = (n + 255) / 256;  // 391 scan blocks
  const int gblocks = n / 16;      // 6250 gemm blocks

  // ---- graph preprocessing (shared by both layers)
  hipMemsetAsync(cnt, 0, MAXB1 * 4, stream);
  count_bkt<<<256, 256, 0, stream>>>(dst, cnt, E, nbk);
  scan_bkt<<<1, 256, 0, stream>>>(cnt, pb_off, cur, nbk);
  stage_bucket<<<256, 256, 0, stream>>>(src, dst, cur, pairs, E, nbk);
  bucket_deg<<<nbk, 256, 0, stream>>>(pairs, pb_off, cnt, deg, dinv, n);
  scan_blocks<<<nb, 256, 0, stream>>>(deg, rowptr, bsum, n);
  scan_top<<<1, 512, 0, stream>>>(bsum, nb);
  add_offsets<<<nb, 256, 0, stream>>>(rowptr, bsum, n, E);
  local_fill2<<<nbk * 2, 256, 0, stream>>>(pairs, pb_off, cnt, rowptr, colidx, n);

  const int pull_blocks = (n * 64 + 255) / 256;  // one wave per node

  // ---- layer 1
  gemm_nodes<128><<<gblocks, 256, 0, stream>>>(x, W1, dinv, B0h);
  gather_agg<<<pull_blocks, 256, 0, stream>>>(rowptr, colidx, B0h, dinv, b1, B1, n);

  // ---- layer 2
  gemm_nodes<64><<<gblocks, 256, 0, stream>>>(B1, W2, dinv, B0h);
  gather_agg<<<pull_blocks, 256, 0, stream>>>(rowptr, colidx, B0h, dinv, b2, B1, n);

  // ---- FC head
  gemm_fc<<<gblocks, 256, 0, stream>>>(B1, Wfc, bfc, out);
}

// Round 9
// 413.914 us; speedup vs baseline: 1.6857x; 1.0732x over previous
//
#include <hip/hip_runtime.h>
#include <hip/hip_fp16.h>

#define HID 64
#define SH 9          // log2(nodes per bucket)
#define BKN 512       // nodes per bucket
#define MAXB1 256     // max buckets supported (n <= 131072)
typedef unsigned int u32;

// ---------------------------------------------------------------- bucket-level histogram
__global__ __launch_bounds__(256) void count_bkt(const int* __restrict__ dst,
                                                 int* __restrict__ cnt,
                                                 int E, int nbk) {
  __shared__ int lc[MAXB1];
  const int t = threadIdx.x;
  for (int b = t; b < nbk; b += 256) lc[b] = 0;
  __syncthreads();
  const int stride = gridDim.x * 256;
  for (int i = blockIdx.x * 256 + t; i < E; i += stride)
    atomicAdd(&lc[dst[i] >> SH], 1);
  __syncthreads();
  for (int b = t; b < nbk; b += 256)
    if (lc[b]) atomicAdd(&cnt[b], lc[b]);
}

// ---------------------------------------------------------------- scan bucket counts
__global__ __launch_bounds__(256) void scan_bkt(const int* __restrict__ cnt,
                                                int* __restrict__ pb_off,
                                                int* __restrict__ cur, int nbk) {
  __shared__ int s[256];
  const int t = threadIdx.x;
  const int c = (t < nbk) ? cnt[t] : 0;
  const int cp = (c + 15) & ~15;  // 16-aligned segment
  s[t] = cp;
  __syncthreads();
  for (int o = 1; o < 256; o <<= 1) {
    const int u = (t >= o) ? s[t - o] : 0;
    __syncthreads();
    s[t] += u;
    __syncthreads();
  }
  if (t < nbk) {
    pb_off[t] = s[t] - cp;
    cur[t * 16] = s[t] - cp;
  }
}

// ---------------------------------------------------------------- LDS-staged bucketing
// packed u32: (dstLocal<<17) | src    (src < 2^17, dstLocal < 512)
__global__ __launch_bounds__(256) void stage_bucket(const int* __restrict__ src,
                                                    const int* __restrict__ dst,
                                                    int* __restrict__ cur,
                                                    u32* __restrict__ pairs,
                                                    int E, int nbk) {
  __shared__ u32 stg[MAXB1 * 17];  // stride 17: conflict-free flusher reads
  __shared__ int lcnt[MAXB1];
  const int t = threadIdx.x;
  for (int b = t; b < nbk; b += 256) lcnt[b] = 0;
  __syncthreads();
  const int stride = gridDim.x * 256;
  const int rounds = (E + stride - 1) / stride;
  int i = blockIdx.x * 256 + t;
  int d = (i < E) ? dst[i] : -1;
  int sv = (i < E) ? src[i] : 0;
  for (int r = 0; r < rounds; ++r) {
    const int inext = i + stride;
    int dn = -1, sn = 0;
    if (inext < E) { dn = dst[inext]; sn = src[inext]; }  // prefetch next round
    if (d >= 0) {
      const int b = d >> SH;
      const u32 v = ((u32)(d & (BKN - 1)) << 17) | (u32)sv;
      const int sl = atomicAdd(&lcnt[b], 1);
      if (sl < 16) stg[b * 17 + sl] = v;
      else pairs[atomicAdd(&cur[b * 16], 1)] = v;  // rare overflow: direct write
    }
    __syncthreads();
    for (int b = t; b < nbk; b += 256) {  // flush full groups of 16
      if (lcnt[b] >= 16) {
        const int pos = atomicAdd(&cur[b * 16], 16);
#pragma unroll
        for (int k = 0; k < 16; ++k) pairs[pos + k] = stg[b * 17 + k];
        lcnt[b] = 0;
      }
    }
    __syncthreads();
    d = dn; sv = sn; i = inext;
  }
  for (int b = t; b < nbk; b += 256) {  // ragged tail
    const int rem = lcnt[b];
    if (rem > 0) {
      const int pos = atomicAdd(&cur[b * 16], rem);
      for (int k = 0; k < rem; ++k) pairs[pos + k] = stg[b * 17 + k];
    }
  }
}

// ---------------------------------------------------------------- per-node degree + dinv
__global__ __launch_bounds__(256) void bucket_deg(const u32* __restrict__ pairs,
                                                  const int* __restrict__ pb_off,
                                                  const int* __restrict__ cnt,
                                                  int* __restrict__ deg,
                                                  float* __restrict__ dinv, int n) {
  __shared__ int ldeg[BKN];
  const int bkt = blockIdx.x;
  const int t = threadIdx.x;
  for (int i = t; i < BKN; i += 256) ldeg[i] = 0;
  __syncthreads();
  const int beg = pb_off[bkt], end = beg + cnt[bkt];
  for (int e = beg + t; e < end; e += 256) atomicAdd(&ldeg[pairs[e] >> 17], 1);
  __syncthreads();
  const int base = bkt * BKN;
  for (int i = t; i < BKN; i += 256) {
    const int node = base + i;
    if (node < n) {
      const int dg = ldeg[i];
      deg[node] = dg;
      dinv[node] = rsqrtf((float)(dg + 1));  // +1 self-loop
    }
  }
}

// ---------------------------------------------------------------- scan (rowptr)
__global__ __launch_bounds__(256) void scan_blocks(const int* __restrict__ deg,
                                                   int* __restrict__ rowptr,
                                                   int* __restrict__ bsum, int n) {
  __shared__ int s[256];
  const int t = threadIdx.x;
  const int i = blockIdx.x * 256 + t;
  const int v = (i < n) ? deg[i] : 0;
  s[t] = v;
  __syncthreads();
  for (int off = 1; off < 256; off <<= 1) {
    const int u = (t >= off) ? s[t - off] : 0;
    __syncthreads();
    s[t] += u;
    __syncthreads();
  }
  if (i < n) rowptr[i] = s[t] - v;
  if (t == 255) bsum[blockIdx.x] = s[255];
}

__global__ __launch_bounds__(512) void scan_top(int* bsum, int nb) {
  __shared__ int s[512];
  const int t = threadIdx.x;
  const int v = (t < nb) ? bsum[t] : 0;
  s[t] = v;
  __syncthreads();
  for (int off = 1; off < 512; off <<= 1) {
    const int u = (t >= off) ? s[t - off] : 0;
    __syncthreads();
    s[t] += u;
    __syncthreads();
  }
  if (t < nb) bsum[t] = s[t] - v;
}

__global__ __launch_bounds__(256) void add_offsets(int* __restrict__ rowptr,
                                                   const int* __restrict__ bsum,
                                                   int n, int E) {
  const int i = blockIdx.x * 256 + threadIdx.x;
  if (i < n) rowptr[i] += bsum[blockIdx.x];
  if (i == 0) rowptr[n] = E;
}

// ---------------------------------------------------------------- exact CSR fill
__global__ __launch_bounds__(256) void local_fill2(const u32* __restrict__ pairs,
                                                   const int* __restrict__ pb_off,
                                                   const int* __restrict__ pb_cnt,
                                                   const int* __restrict__ rowptr,
                                                   int* __restrict__ colidx, int n) {
  __shared__ int lcur[BKN / 2];
  const int bkt = blockIdx.x >> 1;
  const int half = blockIdx.x & 1;
  const int nb0 = bkt * BKN + half * (BKN / 2);
  const int t = threadIdx.x;
  if (t < BKN / 2) {
    const int node = nb0 + t;
    lcur[t] = (node < n) ? rowptr[node] : 0;
  }
  __syncthreads();
  const int beg = pb_off[bkt], end = beg + pb_cnt[bkt];
  for (int e = beg + t; e < end; e += 256) {
    const u32 p = pairs[e];
    const int dloc = (int)(p >> 17);
    if ((dloc >> 8) == half) {
      const int pos = atomicAdd(&lcur[dloc & 255], 1);
      colidx[pos] = (int)(p & 0x1FFFF);
    }
  }
}

// ---------------------------------------------------------------- dense transform
// g[i, c] = fp16( dinv[i] * sum_k x[i,k] * W[k,c] )
template <int K>
__global__ __launch_bounds__(256) void gemm_nodes(const float* __restrict__ x,
                                                  const float* __restrict__ W,
                                                  const float* __restrict__ dinv,
                                                  __half* __restrict__ out) {
  __shared__ float Wl[K * 64];
  __shared__ float xl[16][K];
  const int tid = threadIdx.x;
  for (int i = tid; i < K * 16; i += 256)
    reinterpret_cast<float4*>(Wl)[i] = reinterpret_cast<const float4*>(W)[i];
  const int row0 = blockIdx.x * 16;
  for (int i = tid; i < 16 * (K / 4); i += 256) {
    const int r = i / (K / 4), q = i % (K / 4);
    reinterpret_cast<float4*>(&xl[r][0])[q] =
        reinterpret_cast<const float4*>(x + (size_t)(row0 + r) * K)[q];
  }
  __syncthreads();
  const int c = tid & 63;
  const int rbase = tid >> 6;
  for (int rr = rbase; rr < 16; rr += 4) {
    float acc = 0.f;
#pragma unroll
    for (int k = 0; k < K; k += 4) {
      const float4 xv = *reinterpret_cast<const float4*>(&xl[rr][k]);
      acc = fmaf(xv.x, Wl[(k + 0) * 64 + c], acc);
      acc = fmaf(xv.y, Wl[(k + 1) * 64 + c], acc);
      acc = fmaf(xv.z, Wl[(k + 2) * 64 + c], acc);
      acc = fmaf(xv.w, Wl[(k + 3) * 64 + c], acc);
    }
    const int grow = row0 + rr;
    out[(size_t)grow * 64 + c] = __float2half(acc * dinv[grow]);
  }
}

// ---------------------------------------------------------------- pull aggregation
// one wave per node, TWO edges per wave: lanes 0-31 = even edges, 32-63 = odd.
// each lane holds a float2 accumulator for feature pair l = lane&31.
__global__ __launch_bounds__(256) void gather_agg(const int* __restrict__ rowptr,
                                                  const int* __restrict__ colidx,
                                                  const __half2* __restrict__ g2,
                                                  const float* __restrict__ dinv,
                                                  const float* __restrict__ bias,
                                                  float* __restrict__ out, int n) {
  const int lane = threadIdx.x & 63;
  const int node = (blockIdx.x * 256 + threadIdx.x) >> 6;
  if (node >= n) return;
  const int h = lane >> 5;   // which edge of each pair this half-wave owns
  const int l = lane & 31;   // feature-pair index
  const int beg = rowptr[node];
  const int end = rowptr[node + 1];
  float2 acc = {0.f, 0.f};
  int e = beg + h;
  for (; e + 6 < end; e += 8) {  // 8 edges per wave-iter, 4 loads in flight/half
    const int s0 = colidx[e + 0], s1 = colidx[e + 2];
    const int s2 = colidx[e + 4], s3 = colidx[e + 6];
    const float2 v0 = __half22float2(g2[(size_t)s0 * 32 + l]);
    const float2 v1 = __half22float2(g2[(size_t)s1 * 32 + l]);
    const float2 v2 = __half22float2(g2[(size_t)s2 * 32 + l]);
    const float2 v3 = __half22float2(g2[(size_t)s3 * 32 + l]);
    acc.x += (v0.x + v1.x) + (v2.x + v3.x);
    acc.y += (v0.y + v1.y) + (v2.y + v3.y);
  }
  for (; e < end; e += 2) {  // ragged tail (per-half predicated)
    const float2 v = __half22float2(g2[(size_t)colidx[e] * 32 + l]);
    acc.x += v.x;
    acc.y += v.y;
  }
  // cross-half combine: both halves end with the full neighbor sum
  acc.x += __shfl_xor(acc.x, 32);
  acc.y += __shfl_xor(acc.y, 32);
  // self-loop
  const float2 sv = __half22float2(g2[(size_t)node * 32 + l]);
  acc.x += sv.x;
  acc.y += sv.y;
  const float di = dinv[node];
  const float2 bb = reinterpret_cast<const float2*>(bias)[l];
  float2 r;
  r.x = fmaxf(fmaf(acc.x, di, bb.x), 0.f);
  r.y = fmaxf(fmaf(acc.y, di, bb.y), 0.f);
  if (h == 0) reinterpret_cast<float2*>(out)[(size_t)node * 32 + l] = r;
}

// ---------------------------------------------------------------- final FC (64 -> 11)
__global__ __launch_bounds__(256) void gemm_fc(const float* __restrict__ h,
                                               const float* __restrict__ W,
                                               const float* __restrict__ b,
                                               float* __restrict__ out) {
  __shared__ float Wl[772];
  __shared__ float xl[16][68];
  const int tid = threadIdx.x;
  for (int i = tid; i < 772; i += 256) Wl[i] = 0.f;
  __syncthreads();
  for (int i = tid; i < 64 * 11; i += 256) Wl[(i / 11) * 12 + (i % 11)] = W[i];
  const int row0 = blockIdx.x * 16;
  for (int i = tid; i < 16 * 16; i += 256) {
    const int r = i >> 4, q = i & 15;
    const float4 v = reinterpret_cast<const float4*>(h + (size_t)(row0 + r) * 64)[q];
    xl[r][q * 4 + 0] = v.x; xl[r][q * 4 + 1] = v.y;
    xl[r][q * 4 + 2] = v.z; xl[r][q * 4 + 3] = v.w;
  }
  __syncthreads();
  const int r = tid >> 4, c = tid & 15;
  float acc = 0.f;
#pragma unroll
  for (int k = 0; k < 64; k += 4) {
    acc = fmaf(xl[r][k + 0], Wl[(k + 0) * 12 + c], acc);
    acc = fmaf(xl[r][k + 1], Wl[(k + 1) * 12 + c], acc);
    acc = fmaf(xl[r][k + 2], Wl[(k + 2) * 12 + c], acc);
    acc = fmaf(xl[r][k + 3], Wl[(k + 3) * 12 + c], acc);
  }
  if (c < 11) out[(size_t)(row0 + r) * 11 + c] = acc + b[c];
}

// ---------------------------------------------------------------- launch
extern "C" void kernel_launch(void* const* d_in, const int* in_sizes, int n_in,
                              void* d_out, int out_size, void* d_ws, size_t ws_size,
                              hipStream_t stream) {
  const float* x   = (const float*)d_in[0];
  const int*   ei  = (const int*)d_in[1];   // [2, E] int32
  const float* W1  = (const float*)d_in[2];
  const float* b1  = (const float*)d_in[3];
  const float* W2  = (const float*)d_in[4];
  const float* b2  = (const float*)d_in[5];
  const float* Wfc = (const float*)d_in[6];
  const float* bfc = (const float*)d_in[7];
  float* out = (float*)d_out;

  const int n = in_sizes[0] / 128;  // 100000
  const int E = in_sizes[1] / 2;    // 3200000
  const int* src = ei;
  const int* dst = ei + E;
  const int nbk = (n + BKN - 1) >> SH;  // 196 buckets

  char* ws = (char*)d_ws;
  size_t o = 0;
  auto alloc = [&](size_t bytes) {
    char* p = ws + o;
    o += (bytes + 255) & ~(size_t)255;
    return p;
  };
  int*    deg    = (int*)   alloc((size_t)n * 4);
  float*  dinv   = (float*) alloc((size_t)n * 4);
  int*    rowptr = (int*)   alloc((size_t)(n + 1) * 4);
  int*    bsum   = (int*)   alloc(512 * 4);
  int*    cnt    = (int*)   alloc(MAXB1 * 4);
  int*    pb_off = (int*)   alloc(MAXB1 * 4);
  int*    cur    = (int*)   alloc(MAXB1 * 16 * 4);          // 64B-padded cursors
  u32*    pairs  = (u32*)   alloc(((size_t)E + 16 * MAXB1) * 4);
  int*    colidx = (int*)   alloc((size_t)E * 4);
  __half* B0h    = (__half*)alloc((size_t)n * HID * 2);     // g in fp16
  float*  B1     = (float*) alloc((size_t)n * HID * 4);     // layer output fp32
  if (o > ws_size) return;

  const int nb = (n + 255) / 256;  // 391 scan blocks
  const int gblocks = n / 16;      // 6250 gemm blocks

  // ---- graph preprocessing (shared by both layers)
  hipMemsetAsync(cnt, 0, MAXB1 * 4, stream);
  count_bkt<<<256, 256, 0, stream>>>(dst, cnt, E, nbk);
  scan_bkt<<<1, 256, 0, stream>>>(cnt, pb_off, cur, nbk);
  stage_bucket<<<256, 256, 0, stream>>>(src, dst, cur, pairs, E, nbk);
  bucket_deg<<<nbk, 256, 0, stream>>>(pairs, pb_off, cnt, deg, dinv, n);
  scan_blocks<<<nb, 256, 0, stream>>>(deg, rowptr, bsum, n);
  scan_top<<<1, 512, 0, stream>>>(bsum, nb);
  add_offsets<<<nb, 256, 0, stream>>>(rowptr, bsum, n, E);
  local_fill2<<<nbk * 2, 256, 0, stream>>>(pairs, pb_off, cnt, rowptr, colidx, n);

  const int pull_blocks = (n * 64 + 255) / 256;  // one wave per node

  // ---- layer 1
  gemm_nodes<128><<<gblocks, 256, 0, stream>>>(x, W1, dinv, B0h);
  gather_agg<<<pull_blocks, 256, 0, stream>>>(rowptr, colidx,
      (const __half2*)B0h, dinv, b1, B1, n);

  // ---- layer 2
  gemm_nodes<64><<<gblocks, 256, 0, stream>>>(B1, W2, dinv, B0h);
  gather_agg<<<pull_blocks, 256, 0, stream>>>(rowptr, colidx,
      (const __half2*)B0h, dinv, b2, B1, n);

  // ---- FC head
  gemm_fc<<<gblocks, 256, 0, stream>>>(B1, Wfc, bfc, out);
}